// Round 1
// baseline (1242.661 us; speedup 1.0000x reference)
//
#include <hip/hip_runtime.h>

// QuantizedEmbedding: gather int4-packed rows (stored as int32 in [-128,127]),
// unpack high/low nibble (trunc-div / positive-mod semantics), dequant with
// per-32-element group scales, write fp32.
//
// VOCAB=128000, DIM=4096, GROUPSIZE=32, PACKED=2048, NGROUPS=128
// indices: [4,4096] int32 ; weight: [VOCAB,2048] int32 ; scales: [VOCAB,128] f32
// out: [4,4096,4096] f32
//
// Memory-bound: ~400 MiB total traffic -> ~65us roofline at 6.3 TB/s.

#define PACKED  2048
#define NGROUPS 128
#define DIM     4096

__global__ __launch_bounds__(256) void qembed_kernel(
    const int*   __restrict__ indices,
    const int*   __restrict__ weight,
    const float* __restrict__ scales,
    float*       __restrict__ out)
{
    const int token = blockIdx.x;
    const int t     = threadIdx.x;          // 0..255

    const int row = indices[token];         // wave-uniform -> scalar path

    // Thread t handles packed elements [8t, 8t+8) -> outputs [16t, 16t+16).
    const int4* wrow = (const int4*)(weight + (long long)row * PACKED);
    int4 w0 = wrow[2 * t];
    int4 w1 = wrow[2 * t + 1];

    // Outputs 16t..16t+15 all fall in group (16t)/32 == t>>1 (16 | 32).
    const float s = scales[(long long)row * NGROUPS + (t >> 1)];

    int w[8] = { w0.x, w0.y, w0.z, w0.w, w1.x, w1.y, w1.z, w1.w };

    float o[16];
#pragma unroll
    for (int i = 0; i < 8; ++i) {
        int wi   = w[i];
        int even = wi / 16;      // trunc toward zero == reference _trunc_div16
        int odd  = wi & 15;      // nonneg remainder == jnp.remainder(w,16)
        o[2 * i]     = (float)(even - 8) * s;
        o[2 * i + 1] = (float)(odd  - 8) * s;
    }

    float4* orow = (float4*)(out + (long long)token * DIM + 16 * t);
#pragma unroll
    for (int i = 0; i < 4; ++i)
        orow[i] = make_float4(o[4 * i], o[4 * i + 1], o[4 * i + 2], o[4 * i + 3]);
}

extern "C" void kernel_launch(void* const* d_in, const int* in_sizes, int n_in,
                              void* d_out, int out_size, void* d_ws, size_t ws_size,
                              hipStream_t stream) {
    const int*   indices = (const int*)d_in[0];
    const int*   weight  = (const int*)d_in[1];
    const float* scales  = (const float*)d_in[2];
    float*       out     = (float*)d_out;

    const int n_tokens = in_sizes[0];       // 16384
    qembed_kernel<<<n_tokens, 256, 0, stream>>>(indices, weight, scales, out);
}